// Round 4
// baseline (203.557 us; speedup 1.0000x reference)
//
#include <hip/hip_runtime.h>

#define DEVFN __device__ __forceinline__

typedef __attribute__((ext_vector_type(8))) short bf16x8;
typedef __attribute__((ext_vector_type(4))) float f32x4;
typedef __attribute__((ext_vector_type(16))) float f32x16;

#define MFMA16(a, b, c) __builtin_amdgcn_mfma_f32_16x16x32_bf16(a, b, c, 0, 0, 0)
#define MFMA32(a, b, c) __builtin_amdgcn_mfma_f32_32x32x16_bf16(a, b, c, 0, 0, 0)

DEVFN unsigned short f2bf(float f) {
  union { float f; unsigned u; } v; v.f = f;
  unsigned r = v.u + 0x7FFFu + ((v.u >> 16) & 1u);
  return (unsigned short)(r >> 16);
}
DEVFN unsigned pack2bf(float a, float b) {
  return (unsigned)f2bf(a) | ((unsigned)f2bf(b) << 16);
}
DEVFN unsigned cvtpk(float lo, float hi) {
  unsigned r;
  asm("v_cvt_pk_bf16_f32 %0, %1, %2" : "=v"(r) : "v"(lo), "v"(hi));
  return r;
}
DEVFN void pl32swap(unsigned& a, unsigned& b) {
  asm("v_permlane32_swap_b32 %0, %1" : "+v"(a), "+v"(b));
}
DEVFN void gll16(const void* g, void* l) {
  __builtin_amdgcn_global_load_lds((__attribute__((address_space(1))) void*)g,
                                   (__attribute__((address_space(3))) void*)l,
                                   16, 0, 0);
}

// ---------------- precompute kernels ----------------

__global__ __launch_bounds__(256) void conv_x_k(const float* __restrict__ x,
                                                unsigned short* __restrict__ xb) {
  int i = (blockIdx.x * 256 + threadIdx.x) * 4;
  float4 v = *(const float4*)(x + i);
  uint2 u;
  u.x = pack2bf(v.x, v.y);
  u.y = pack2bf(v.z, v.w);
  *(uint2*)(xb + i) = u;
}

// WT[n][k] = (bf16) W[k][n], 64x64 tiles through LDS
__global__ __launch_bounds__(256) void transp_k(
    const float* __restrict__ Wq, const float* __restrict__ Wk,
    const float* __restrict__ Wv, const float* __restrict__ Wo,
    unsigned short* __restrict__ Tq, unsigned short* __restrict__ Tk,
    unsigned short* __restrict__ Tv, unsigned short* __restrict__ To) {
  __shared__ unsigned short t[64 * 65];
  int z = blockIdx.z;
  const float* src = (z == 0) ? Wq : (z == 1) ? Wk : (z == 2) ? Wv : Wo;
  unsigned short* dst = (z == 0) ? Tq : (z == 1) ? Tk : (z == 2) ? Tv : To;
  int k0 = blockIdx.x * 64, n0 = blockIdx.y * 64;
  int tid = threadIdx.x;
#pragma unroll
  for (int i = 0; i < 16; ++i) {
    int flat = i * 256 + tid;
    int r = flat >> 6, cc = flat & 63;
    t[cc * 65 + r] = f2bf(src[(size_t)(k0 + r) * 1024 + n0 + cc]);
  }
  __syncthreads();
#pragma unroll
  for (int i = 0; i < 16; ++i) {
    int flat = i * 256 + tid;
    int rr = flat >> 6, cc = flat & 63;
    dst[(size_t)(n0 + rr) * 1024 + k0 + cc] = t[rr * 65 + cc];
  }
}

__global__ __launch_bounds__(256) void rope_k(float2* __restrict__ rtab) {
  int idx = blockIdx.x * 256 + threadIdx.x;  // 2048*32
  int s = idx >> 5, j = idx & 31;
  float freq = expf(-0.28782313714981824f * (float)j);
  float ang = (float)s * freq;
  rtab[idx] = make_float2(sinf(ang), cosf(ang));
}

// ---------------- GEMM: C[8192,1024] = A(bf16) @ W, B given as WT[n][k] ----
template <int MODE>
__global__ __launch_bounds__(256) void gemm_k(
    const unsigned short* __restrict__ A, const unsigned short* __restrict__ WT,
    void* __restrict__ outp, const float2* __restrict__ rtab) {
  __shared__ unsigned short At[128 * 64];
  __shared__ unsigned short Bt[128 * 64];
  const int tid = threadIdx.x;
  const int w = tid >> 6, lane = tid & 63, g = lane >> 4, c = lane & 15;
  const int wr = w >> 1, wc = w & 1;
  const int m0 = blockIdx.x * 128, n0 = blockIdx.y * 128;

  f32x4 zero = {0.f, 0.f, 0.f, 0.f};
  f32x4 acc[4][4];
#pragma unroll
  for (int i = 0; i < 4; ++i)
#pragma unroll
    for (int j = 0; j < 4; ++j) acc[i][j] = zero;

  for (int k0 = 0; k0 < 1024; k0 += 64) {
#pragma unroll
    for (int p = 0; p < 4; ++p) {
      int i = p * 256 + tid;
      int row = i >> 3, ls = i & 7;
      size_t off = ((size_t)(m0 + row) * 1024 + k0) * 2 + ((ls ^ (row & 7)) << 4);
      gll16((const char*)A + off, (char*)At + p * 4096 + w * 1024);
      size_t offb = ((size_t)(n0 + row) * 1024 + k0) * 2 + ((ls ^ (row & 7)) << 4);
      gll16((const char*)WT + offb, (char*)Bt + p * 4096 + w * 1024);
    }
    __syncthreads();
#pragma unroll
    for (int ks = 0; ks < 2; ++ks) {
      bf16x8 af[4], bfv[4];
#pragma unroll
      for (int am = 0; am < 4; ++am) {
        int row = wr * 64 + am * 16 + c;
        af[am] = *(const bf16x8*)(At + row * 64 + ((((ks << 2) | g) ^ (row & 7)) << 3));
      }
#pragma unroll
      for (int bn = 0; bn < 4; ++bn) {
        int row = wc * 64 + bn * 16 + c;
        bfv[bn] = *(const bf16x8*)(Bt + row * 64 + ((((ks << 2) | g) ^ (row & 7)) << 3));
      }
#pragma unroll
      for (int am = 0; am < 4; ++am)
#pragma unroll
        for (int bn = 0; bn < 4; ++bn)
          acc[am][bn] = MFMA16(af[am], bfv[bn], acc[am][bn]);
    }
    __syncthreads();
  }

  if (MODE == 0 || MODE == 1) {
    unsigned short* outb = (unsigned short*)outp;
#pragma unroll
    for (int am = 0; am < 4; ++am)
#pragma unroll
      for (int bp = 0; bp < 2; ++bp) {
        int col = n0 + wc * 64 + bp * 16 + c;
        int h = col >> 6, j = col & 63;
#pragma unroll
        for (int r = 0; r < 4; ++r) {
          int row = m0 + wr * 64 + am * 16 + (g << 2) + r;
          int b = row >> 11, s = row & 2047;
          float x1 = acc[am][bp][r], x2 = acc[am][bp + 2][r];
          float2 sc = rtab[s * 32 + j];
          float o1 = sc.y * x1 - sc.x * x2;
          float o2 = sc.x * x1 + sc.y * x2;
          if (MODE == 0) {
            o1 *= 0.18033688011112042f;  // 0.125 * log2(e)
            o2 *= 0.18033688011112042f;
          }
          size_t base = (((size_t)(b * 16 + h)) * 2048 + s) * 64;
          outb[base + j] = f2bf(o1);
          outb[base + 32 + j] = f2bf(o2);
        }
      }
  } else if (MODE == 2) {
    unsigned short* outb = (unsigned short*)outp;
#pragma unroll
    for (int am = 0; am < 4; ++am)
#pragma unroll
      for (int bn = 0; bn < 4; ++bn) {
        int col = n0 + wc * 64 + bn * 16 + c;
        int h = col >> 6, d = col & 63;
        int row0 = m0 + wr * 64 + am * 16 + (g << 2);
        int b = row0 >> 11, s0 = row0 & 2047;
        uint2 u;
        u.x = pack2bf(acc[am][bn][0], acc[am][bn][1]);
        u.y = pack2bf(acc[am][bn][2], acc[am][bn][3]);
        *(uint2*)(outb + ((size_t)((b * 16 + h) * 64 + d)) * 2048 + s0) = u;
      }
  } else {
    float* outf = (float*)outp;
#pragma unroll
    for (int am = 0; am < 4; ++am)
#pragma unroll
      for (int bn = 0; bn < 4; ++bn)
#pragma unroll
        for (int r = 0; r < 4; ++r)
          outf[(size_t)(m0 + wr * 64 + am * 16 + (g << 2) + r) * 1024 +
               (n0 + wc * 64 + bn * 16 + c)] = acc[am][bn][r];
  }
}

// ---------------- flash attention (causal, 32x32 MFMA, in-reg softmax) -----
// Q,K: [BH][2048][64] bf16 (Q pre-scaled by 0.125*log2e); VT: [BH][64][2048]
// ctx: [B][S][H*64] bf16.
// LDS K/V tiles are SLOT-MAJOR: [8 slots of k][64 rows][16B] -> fragment
// reads are 512B-contiguous per 32-lane group (conflict-free, no addr math).
// Softmax: q lane-local (swapped mfma32); row-sum via ones-MFMA into lacc
// (no VALU adds / shuffles); defer-max rescale; P->PV frags via cvt_pk +
// permlane32_swap in-register.
__global__ __launch_bounds__(256, 4) void attn_k(
    const unsigned short* __restrict__ Q, const unsigned short* __restrict__ K,
    const unsigned short* __restrict__ VT, unsigned short* __restrict__ ctx) {
  __shared__ unsigned short Kt[2][8 * 64 * 8];  // [slot][row][8 bf16]
  __shared__ unsigned short Vt[2][8 * 64 * 8];

  const int fid = blockIdx.x + (blockIdx.y << 4);
  const int xcd = fid & 7, j = fid >> 3;
  const int bh = (xcd << 3) + (j >> 4);  // 8 heads per XCD (K/V L2-resident)
  const int p = j & 15;
  const int qtB = 31 - p;

  const int tid = threadIdx.x;
  const int w = tid >> 6, lane = tid & 63;
  const int hi = lane >> 5, c5 = lane & 31;
  const int myIsB = ((w >> 1) == (fid & 1));
  const int myTile = myIsB ? qtB : p;
  const int myLast = myTile;
  const int qw = myTile * 64 + (w & 1) * 32;

  const unsigned short* Qbh = Q + (size_t)bh * 2048 * 64;
  const unsigned short* Kbh = K + (size_t)bh * 2048 * 64;
  const unsigned short* VTbh = VT + (size_t)bh * 64 * 2048;

  // Q fragment (B-operand): lane holds Q[qw+c5][kb*16 + hi*8 + j], j=0..7
  bf16x8 qf[4];
#pragma unroll
  for (int kb = 0; kb < 4; ++kb)
    qf[kb] = *(const bf16x8*)(Qbh + (size_t)(qw + c5) * 64 + kb * 16 + hi * 8);

  // ones A-fragment for l-accumulation (bf16 1.0 = 0x3F80)
  bf16x8 ones;
#pragma unroll
  for (int i = 0; i < 8; ++i) ones[i] = (short)0x3F80;

  f32x16 zacc;
#pragma unroll
  for (int i = 0; i < 16; ++i) zacc[i] = 0.f;
  f32x16 oacc[2], lacc;
  oacc[0] = zacc; oacc[1] = zacc; lacc = zacc;
  float m_run = -1e30f;

  auto stage = [&](int st, int buf) {
    const char* ksrc = (const char*)Kbh + (size_t)(st * 64 + lane) * 128;
    const char* vsrc = (const char*)VTbh + (size_t)lane * 4096 + (size_t)st * 128;
#pragma unroll
    for (int pp = 0; pp < 2; ++pp) {
      const int m = pp * 4 + w;  // slot index
      gll16(ksrc + m * 16, (char*)(&Kt[buf][0]) + m * 1024);
      gll16(vsrc + m * 16, (char*)(&Vt[buf][0]) + m * 1024);
    }
  };

  stage(0, 0);
  __syncthreads();

  for (int st = 0; st <= qtB; ++st) {
    const int cur = st & 1;
    if (st < qtB) stage(st + 1, cur ^ 1);

    if (st <= myLast) {
      const unsigned short* Kb_ = &Kt[cur][0];
      const unsigned short* Vb_ = &Vt[cur][0];

      // QK^T: sacc[t] = S^T[kv = st*64 + t*32 + (reg map)][q = qw + c5]
      f32x16 sacc[2];
      __builtin_amdgcn_s_setprio(1);
#pragma unroll
      for (int t = 0; t < 2; ++t) {
        const int ro = (t * 32 + c5) * 8;
        bf16x8 kf0 = *(const bf16x8*)(Kb_ + hi * 512 + ro);
        sacc[t] = MFMA32(kf0, qf[0], zacc);
#pragma unroll
        for (int kb = 1; kb < 4; ++kb) {
          bf16x8 kf = *(const bf16x8*)(Kb_ + (2 * kb + hi) * 512 + ro);
          sacc[t] = MFMA32(kf, qf[kb], sacc[t]);
        }
      }
      __builtin_amdgcn_s_setprio(0);

      // causal mask (diagonal step only)
      if (st == myLast) {
        const int q = qw + c5;
#pragma unroll
        for (int t = 0; t < 2; ++t) {
          const int kvb = st * 64 + t * 32 + (hi << 2);
#pragma unroll
          for (int i = 0; i < 16; ++i) {
            int kv = kvb + (i & 3) + ((i >> 2) << 3);
            if (kv > q) sacc[t][i] = -1e30f;
          }
        }
      }

      // online softmax: q lane-local; rows split across hi halves only
      float vmax = fmaxf(sacc[0][0], sacc[0][1]);
#pragma unroll
      for (int t = 0; t < 2; ++t)
#pragma unroll
        for (int i = (t == 0 ? 2 : 0); i < 16; i += 2)
          vmax = fmaxf(vmax, fmaxf(sacc[t][i], sacc[t][i + 1]));  // v_max3
      vmax = fmaxf(vmax, __shfl_xor(vmax, 32, 64));
      if (!__all(vmax <= m_run + 8.0f)) {  // defer-max (log2 domain, THR=8)
        float m_new = fmaxf(m_run, vmax);
        float alpha = exp2f(m_run - m_new);
#pragma unroll
        for (int i = 0; i < 16; ++i) {
          oacc[0][i] *= alpha;
          oacc[1][i] *= alpha;
          lacc[i] *= alpha;
        }
        m_run = m_new;
      }
#pragma unroll
      for (int t = 0; t < 2; ++t)
#pragma unroll
        for (int i = 0; i < 16; ++i) sacc[t][i] = exp2f(sacc[t][i] - m_run);

      // P -> bf16 PV B-fragments in-register: 16 cvt_pk + 8 permlane32_swap
      unsigned pword[4][4];  // [kb][word]
#pragma unroll
      for (int t = 0; t < 2; ++t) {
        unsigned X[4][2];
#pragma unroll
        for (int u = 0; u < 4; ++u)
#pragma unroll
          for (int wp = 0; wp < 2; ++wp)
            X[u][wp] = cvtpk(sacc[t][u * 4 + 2 * wp], sacc[t][u * 4 + 2 * wp + 1]);
#pragma unroll
        for (int par = 0; par < 2; ++par) {
          const int kb = 2 * t + par;
#pragma unroll
          for (int wp = 0; wp < 2; ++wp) {
            unsigned a = X[2 * par][wp], b2 = X[2 * par + 1][wp];
            pl32swap(a, b2);
            pword[kb][wp] = a;
            pword[kb][wp + 2] = b2;
          }
        }
      }

      // PV: O^T[d][q] += V^T[d][kv] . P[kv][q]; l via ones-MFMA
      __builtin_amdgcn_s_setprio(1);
#pragma unroll
      for (int kb = 0; kb < 4; ++kb) {
        union { unsigned u[4]; bf16x8 v; } pw;
#pragma unroll
        for (int k2 = 0; k2 < 4; ++k2) pw.u[k2] = pword[kb][k2];
        const int so = (2 * kb + hi) * 512;
#pragma unroll
        for (int dt = 0; dt < 2; ++dt) {
          bf16x8 vf = *(const bf16x8*)(Vb_ + so + (dt * 32 + c5) * 8);
          oacc[dt] = MFMA32(vf, pw.v, oacc[dt]);
        }
        lacc = MFMA32(ones, pw.v, lacc);
      }
      __builtin_amdgcn_s_setprio(0);
    }
    __syncthreads();
  }

  // epilogue: O^T[d][q] / l -> ctx[b][q][h*64+d]
  const int b = bh >> 4, h = bh & 15;
  const float linv = 1.f / lacc[0];
  unsigned short* crow = ctx + ((size_t)(b * 2048 + qw + c5)) * 1024 + h * 64;
#pragma unroll
  for (int dt = 0; dt < 2; ++dt)
#pragma unroll
    for (int u = 0; u < 4; ++u) {
      int d0 = dt * 32 + 8 * u + 4 * hi;
      uint2 o;
      o.x = cvtpk(oacc[dt][4 * u] * linv, oacc[dt][4 * u + 1] * linv);
      o.y = cvtpk(oacc[dt][4 * u + 2] * linv, oacc[dt][4 * u + 3] * linv);
      *(uint2*)(crow + d0) = o;
    }
}

// ---------------- launcher ----------------

extern "C" void kernel_launch(void* const* d_in, const int* in_sizes, int n_in,
                              void* d_out, int out_size, void* d_ws, size_t ws_size,
                              hipStream_t stream) {
  (void)in_sizes; (void)n_in; (void)out_size; (void)ws_size;
  const float* x = (const float*)d_in[0];
  const float* Wq = (const float*)d_in[1];
  const float* Wk = (const float*)d_in[2];
  const float* Wv = (const float*)d_in[3];
  const float* Wo = (const float*)d_in[4];
  char* ws = (char*)d_ws;
  const size_t MiB = 1024 * 1024;
  unsigned short* xb  = (unsigned short*)(ws);             // 16 MiB
  unsigned short* WTq = (unsigned short*)(ws + 16 * MiB);  // 2 MiB each
  unsigned short* WTk = (unsigned short*)(ws + 18 * MiB);
  unsigned short* WTv = (unsigned short*)(ws + 20 * MiB);
  unsigned short* WTo = (unsigned short*)(ws + 22 * MiB);
  unsigned short* Qb  = (unsigned short*)(ws + 24 * MiB);  // 16 MiB each
  unsigned short* Kb  = (unsigned short*)(ws + 40 * MiB);
  unsigned short* VTb = (unsigned short*)(ws + 56 * MiB);
  unsigned short* ctx = (unsigned short*)(ws + 72 * MiB);
  float2* rtab = (float2*)(ws + 88 * MiB);                 // 512 KiB

  conv_x_k<<<8192, 256, 0, stream>>>(x, xb);
  transp_k<<<dim3(16, 16, 4), 256, 0, stream>>>(Wq, Wk, Wv, Wo, WTq, WTk, WTv, WTo);
  rope_k<<<256, 256, 0, stream>>>(rtab);
  gemm_k<0><<<dim3(64, 8), 256, 0, stream>>>(xb, WTq, Qb, rtab);
  gemm_k<1><<<dim3(64, 8), 256, 0, stream>>>(xb, WTk, Kb, rtab);
  gemm_k<2><<<dim3(64, 8), 256, 0, stream>>>(xb, WTv, VTb, rtab);
  attn_k<<<dim3(16, 64), 256, 0, stream>>>(Qb, Kb, VTb, ctx);
  gemm_k<3><<<dim3(64, 8), 256, 0, stream>>>(ctx, WTo, d_out, rtab);
}